// Round 8
// baseline (219.411 us; speedup 1.0000x reference)
//
#include <hip/hip_runtime.h>

#define N_NODES 20000
#define D_FEAT 256
#define N_SUPPORT 3
#define N_EDGES 320000
#define OUT_DIM 256
#define TOTAL_E (N_SUPPORT * N_EDGES)
#define CAP 64                      // per-(s,dst) bucket; mean 16, P(>64) ~ 1e-9
#define KDIM (N_SUPPORT * D_FEAT)   // 768
#define HPAD (KDIM + 8)             // 776 shorts; rows stay 16B-aligned
#define TILE 16

typedef __attribute__((ext_vector_type(8))) short short8;
typedef __attribute__((ext_vector_type(8))) unsigned short ushort8;
typedef __attribute__((ext_vector_type(4))) float f32x4;

__device__ inline unsigned short f2bf(float f) {
    unsigned int u = __float_as_uint(f);
    u += 0x7fff + ((u >> 16) & 1);  // round-to-nearest-even
    return (unsigned short)(u >> 16);
}
__device__ inline float bf2f(unsigned short u) {
    return __uint_as_float(((unsigned int)u) << 16);
}

// ---------------- prep: convert_x | convert_w | fill_edges fused by block range ----------------
#define NB_X 5000   // 20000*256/4 float4 / 256 threads
#define NB_W (N_SUPPORT * D_FEAT)   // 768
#define NB_F (TOTAL_E / 256)        // 3750

__global__ void __launch_bounds__(256) prep(const float* __restrict__ x, const float* __restrict__ W,
        const int* __restrict__ src, const int* __restrict__ dst, const float* __restrict__ w,
        unsigned short* __restrict__ xb, unsigned short* __restrict__ wt,
        int* __restrict__ cursor, unsigned int* __restrict__ epack) {
    const int bid = blockIdx.x;
    const int tid = threadIdx.x;
    if (bid < NB_X) {
        const int i = bid * 256 + tid;
        float4 v = ((const float4*)x)[i];
        ushort4 o;
        o.x = f2bf(v.x); o.y = f2bf(v.y); o.z = f2bf(v.z); o.w = f2bf(v.w);
        ((ushort4*)xb)[i] = o;
    } else if (bid < NB_X + NB_W) {
        const int row = bid - NB_X;        // s*256 + k
        const int s = row >> 8, k = row & 255;
        wt[((size_t)s * OUT_DIM + tid) * D_FEAT + k] = f2bf(W[(size_t)row * OUT_DIM + tid]);
    } else {
        const int i = (bid - NB_X - NB_W) * 256 + tid;
        const int s = i / N_EDGES;
        const int b = s * N_NODES + dst[i];
        const int pos = atomicAdd(&cursor[b], 1);
        if (pos < CAP)
            epack[(size_t)b * CAP + pos] = (unsigned int)src[i] | (((unsigned int)f2bf(w[i])) << 16);
    }
}

// ---------------- fused: gather-aggregate h (LDS) then h @ W via MFMA ----------------
// 16-node dst tile, 256 threads (4 waves). Phase 1: wave = 4 nodes, 3 support
// streams interleaved (6 row-loads in flight per lane). Phase 2: wave = 4 n-tiles.
__global__ void __launch_bounds__(256) fused_gather_gemm(
        const unsigned short* __restrict__ xb, const unsigned short* __restrict__ wt,
        const int* __restrict__ cursor, const unsigned int* __restrict__ epack,
        float* __restrict__ out) {
    __shared__ unsigned short h[TILE][HPAD];   // 24,832 B
    const int n0 = blockIdx.x * TILE;
    const int wid = threadIdx.x >> 6;
    const int lane = threadIdx.x & 63;
    const int half = lane >> 5;
    const int l32 = lane & 31;
    const int xoff = l32 * 8;

    // ---- phase 1 ----
    for (int ni = 0; ni < 4; ++ni) {
        const int lr = wid * 4 + ni;
        const int node = n0 + lr;
        int c0 = cursor[node];               if (c0 > CAP) c0 = CAP;
        int c1 = cursor[N_NODES + node];     if (c1 > CAP) c1 = CAP;
        int c2 = cursor[2 * N_NODES + node]; if (c2 > CAP) c2 = CAP;
        const unsigned int* ep0 = epack + (size_t)node * CAP;
        const unsigned int* ep1 = epack + (size_t)(N_NODES + node) * CAP;
        const unsigned int* ep2 = epack + (size_t)(2 * N_NODES + node) * CAP;

        float a0[8], a1[8], a2[8];
#pragma unroll
        for (int j = 0; j < 8; ++j) { a0[j] = 0.f; a1[j] = 0.f; a2[j] = 0.f; }

        int minc = c0 < c1 ? c0 : c1; if (c2 < minc) minc = c2;
        int maxc = c0 > c1 ? c0 : c1; if (c2 > maxc) maxc = c2;

        int it = half;
        // main loop: all 3 streams active, 2-unrolled -> 6 independent row loads
        for (; it + 2 < minc; it += 4) {
            const unsigned int p0a = ep0[it], p0b = ep0[it + 2];
            const unsigned int p1a = ep1[it], p1b = ep1[it + 2];
            const unsigned int p2a = ep2[it], p2b = ep2[it + 2];
            ushort8 v0a = *(const ushort8*)(xb + (size_t)(p0a & 0xFFFFu) * D_FEAT + xoff);
            ushort8 v0b = *(const ushort8*)(xb + (size_t)(p0b & 0xFFFFu) * D_FEAT + xoff);
            ushort8 v1a = *(const ushort8*)(xb + (size_t)(p1a & 0xFFFFu) * D_FEAT + xoff);
            ushort8 v1b = *(const ushort8*)(xb + (size_t)(p1b & 0xFFFFu) * D_FEAT + xoff);
            ushort8 v2a = *(const ushort8*)(xb + (size_t)(p2a & 0xFFFFu) * D_FEAT + xoff);
            ushort8 v2b = *(const ushort8*)(xb + (size_t)(p2b & 0xFFFFu) * D_FEAT + xoff);
            const float w0a = __uint_as_float(p0a & 0xFFFF0000u);
            const float w0b = __uint_as_float(p0b & 0xFFFF0000u);
            const float w1a = __uint_as_float(p1a & 0xFFFF0000u);
            const float w1b = __uint_as_float(p1b & 0xFFFF0000u);
            const float w2a = __uint_as_float(p2a & 0xFFFF0000u);
            const float w2b = __uint_as_float(p2b & 0xFFFF0000u);
#pragma unroll
            for (int j = 0; j < 8; ++j) {
                a0[j] += w0a * bf2f(v0a[j]) + w0b * bf2f(v0b[j]);
                a1[j] += w1a * bf2f(v1a[j]) + w1b * bf2f(v1b[j]);
                a2[j] += w2a * bf2f(v2a[j]) + w2b * bf2f(v2b[j]);
            }
        }
        // cleanup: guarded per stream, same parity
        for (; it < maxc; it += 2) {
            if (it < c0) {
                const unsigned int p = ep0[it];
                ushort8 v = *(const ushort8*)(xb + (size_t)(p & 0xFFFFu) * D_FEAT + xoff);
                const float wv = __uint_as_float(p & 0xFFFF0000u);
#pragma unroll
                for (int j = 0; j < 8; ++j) a0[j] += wv * bf2f(v[j]);
            }
            if (it < c1) {
                const unsigned int p = ep1[it];
                ushort8 v = *(const ushort8*)(xb + (size_t)(p & 0xFFFFu) * D_FEAT + xoff);
                const float wv = __uint_as_float(p & 0xFFFF0000u);
#pragma unroll
                for (int j = 0; j < 8; ++j) a1[j] += wv * bf2f(v[j]);
            }
            if (it < c2) {
                const unsigned int p = ep2[it];
                ushort8 v = *(const ushort8*)(xb + (size_t)(p & 0xFFFFu) * D_FEAT + xoff);
                const float wv = __uint_as_float(p & 0xFFFF0000u);
#pragma unroll
                for (int j = 0; j < 8; ++j) a2[j] += wv * bf2f(v[j]);
            }
        }

        // combine halves, write h row slices
#pragma unroll
        for (int j = 0; j < 8; ++j) {
            a0[j] += __shfl_xor(a0[j], 32, 64);
            a1[j] += __shfl_xor(a1[j], 32, 64);
            a2[j] += __shfl_xor(a2[j], 32, 64);
        }
        if (half == 0) {
            ushort8 o0, o1, o2;
#pragma unroll
            for (int j = 0; j < 8; ++j) { o0[j] = f2bf(a0[j]); o1[j] = f2bf(a1[j]); o2[j] = f2bf(a2[j]); }
            *(ushort8*)&h[lr][0 * D_FEAT + xoff] = o0;
            *(ushort8*)&h[lr][1 * D_FEAT + xoff] = o1;
            *(ushort8*)&h[lr][2 * D_FEAT + xoff] = o2;
        }
    }
    __syncthreads();

    // ---- phase 2: out_tile[16][256] = h @ W ----
    const int ntg = wid;                 // n-tiles ntg*4 .. ntg*4+3
    const int cit = lane & 15;
    const int kgrp = (lane >> 4) * 8;

    f32x4 acc[4];
#pragma unroll
    for (int j = 0; j < 4; ++j) acc[j] = (f32x4){0.f, 0.f, 0.f, 0.f};

#pragma unroll
    for (int kk = 0; kk < KDIM / 32; ++kk) {   // 24 k-steps
        const int k0 = kk * 32;
        short8 av = *(const short8*)&h[cit][k0 + kgrp];
        const int s = k0 >> 8;
        const int kp = (k0 & 255) + kgrp;
        const short* bbase = (const short*)wt + (size_t)s * D_FEAT * OUT_DIM
                           + (size_t)cit * D_FEAT + kp;
#pragma unroll
        for (int j = 0; j < 4; ++j) {
            const int nt = ntg * 4 + j;
            short8 bv = *(const short8*)(bbase + (size_t)nt * 16 * D_FEAT);
            acc[j] = __builtin_amdgcn_mfma_f32_16x16x32_bf16(av, bv, acc[j], 0, 0, 0);
        }
    }

    // C-write (round-2-verified mapping): row = rbase+r, col = nt*16 + cit
    const int rbase = (lane >> 4) * 4;
#pragma unroll
    for (int j = 0; j < 4; ++j) {
        const int col = (ntg * 4 + j) * 16 + cit;
#pragma unroll
        for (int r = 0; r < 4; ++r) {
            out[(size_t)(n0 + rbase + r) * OUT_DIM + col] = acc[j][r];
        }
    }
}

extern "C" void kernel_launch(void* const* d_in, const int* in_sizes, int n_in,
                              void* d_out, int out_size, void* d_ws, size_t ws_size,
                              hipStream_t stream) {
    const float* x        = (const float*)d_in[0];
    const int*   edge_src = (const int*)d_in[1];
    const int*   edge_dst = (const int*)d_in[2];
    const float* edge_w   = (const float*)d_in[3];
    const float* W        = (const float*)d_in[4];
    float* out = (float*)d_out;

    char* ws = (char*)d_ws;
    unsigned short* xb     = (unsigned short*)(ws);              // 10,240,000 B
    unsigned short* wt     = (unsigned short*)(ws + 10240000);   //    393,216 B
    int*            cursor = (int*)(ws + 10633216);              //    240,000 B
    unsigned int*   epack  = (unsigned int*)(ws + 10873216);     // 15,360,000 B

    hipMemsetAsync(cursor, 0, 240000, stream);

    prep<<<NB_X + NB_W + NB_F, 256, 0, stream>>>(x, W, edge_src, edge_dst, edge_w,
                                                 xb, wt, cursor, epack);

    fused_gather_gemm<<<N_NODES / TILE, 256, 0, stream>>>(xb, wt, cursor, epack, out);
}

// Round 9
// 185.887 us; speedup vs baseline: 1.1803x; 1.1803x over previous
//
#include <hip/hip_runtime.h>

#define N_NODES 20000
#define D_FEAT 256
#define N_SUPPORT 3
#define N_EDGES 320000
#define OUT_DIM 256
#define TOTAL_E (N_SUPPORT * N_EDGES)
#define CAP 64                      // per-(s,dst) bucket; mean 16, P(>64) ~ 1e-9
#define KDIM (N_SUPPORT * D_FEAT)   // 768
#define HPAD (KDIM + 8)             // 776 shorts; rows 16B-aligned, 2-way bank (free)
#define TILE 16

typedef __attribute__((ext_vector_type(8))) short short8;
typedef __attribute__((ext_vector_type(8))) unsigned short ushort8;
typedef __attribute__((ext_vector_type(4))) float f32x4;

__device__ inline unsigned short f2bf(float f) {
    unsigned int u = __float_as_uint(f);
    u += 0x7fff + ((u >> 16) & 1);  // round-to-nearest-even
    return (unsigned short)(u >> 16);
}
__device__ inline float bf2f(unsigned short u) {
    return __uint_as_float(((unsigned int)u) << 16);
}

// ---------------- prep: convert_x | convert_w | fill_edges fused by block range ----------------
#define NB_X 5000                   // 20000*256/4 float4 / 256 threads
#define NB_W (N_SUPPORT * D_FEAT)   // 768
#define NB_F (TOTAL_E / 256)        // 3750

__global__ void __launch_bounds__(256) prep(const float* __restrict__ x, const float* __restrict__ W,
        const int* __restrict__ src, const int* __restrict__ dst, const float* __restrict__ w,
        unsigned short* __restrict__ xb, unsigned short* __restrict__ wt,
        int* __restrict__ cursor, unsigned int* __restrict__ epack) {
    const int bid = blockIdx.x;
    const int tid = threadIdx.x;
    if (bid < NB_X) {
        const int i = bid * 256 + tid;
        float4 v = ((const float4*)x)[i];
        ushort4 o;
        o.x = f2bf(v.x); o.y = f2bf(v.y); o.z = f2bf(v.z); o.w = f2bf(v.w);
        ((ushort4*)xb)[i] = o;
    } else if (bid < NB_X + NB_W) {
        const int row = bid - NB_X;        // s*256 + k
        const int s = row >> 8, k = row & 255;
        wt[((size_t)s * OUT_DIM + tid) * D_FEAT + k] = f2bf(W[(size_t)row * OUT_DIM + tid]);
    } else {
        const int i = (bid - NB_X - NB_W) * 256 + tid;
        const int s = i / N_EDGES;
        const int b = s * N_NODES + dst[i];
        const int pos = atomicAdd(&cursor[b], 1);
        if (pos < CAP)
            epack[(size_t)b * CAP + pos] = (unsigned int)src[i] | (((unsigned int)f2bf(w[i])) << 16);
    }
}

// ---------------- fused: gather-aggregate h (LDS) then h @ W via MFMA ----------------
// 16-node dst tile, 512 threads (8 waves). Phase 1: each 32-lane half owns ONE
// node (lr = wid*2 + half): 3 supports serial, ILP-4 via uint4 record loads,
// no shfl, direct LDS row-slice writes. Phase 2: wave = 2 n-tiles x 24 k-steps.
__global__ void __launch_bounds__(512) fused_gather_gemm(
        const unsigned short* __restrict__ xb, const unsigned short* __restrict__ wt,
        const int* __restrict__ cursor, const unsigned int* __restrict__ epack,
        float* __restrict__ out) {
    __shared__ unsigned short h[TILE][HPAD];   // 24,832 B
    const int n0 = blockIdx.x * TILE;
    const int wid = threadIdx.x >> 6;
    const int lane = threadIdx.x & 63;
    const int half = lane >> 5;
    const int l32 = lane & 31;
    const int xoff = l32 * 8;                  // 16 B slice of the 512 B x-row

    // ---- phase 1: half -> one node, 3 supports serial ----
    const int lr = wid * 2 + half;
    const int node = n0 + lr;
#pragma unroll
    for (int s = 0; s < N_SUPPORT; ++s) {
        const int b = s * N_NODES + node;
        int cnt = cursor[b]; if (cnt > CAP) cnt = CAP;
        const unsigned int* ep = epack + (size_t)b * CAP;

        float a[8];
#pragma unroll
        for (int j = 0; j < 8; ++j) a[j] = 0.f;

        int it = 0;
        for (; it + 3 < cnt; it += 4) {        // 4 independent x-row loads in flight
            const uint4 pk = *(const uint4*)(ep + it);
            ushort8 v0 = *(const ushort8*)(xb + (size_t)(pk.x & 0xFFFFu) * D_FEAT + xoff);
            ushort8 v1 = *(const ushort8*)(xb + (size_t)(pk.y & 0xFFFFu) * D_FEAT + xoff);
            ushort8 v2 = *(const ushort8*)(xb + (size_t)(pk.z & 0xFFFFu) * D_FEAT + xoff);
            ushort8 v3 = *(const ushort8*)(xb + (size_t)(pk.w & 0xFFFFu) * D_FEAT + xoff);
            const float w0 = __uint_as_float(pk.x & 0xFFFF0000u);
            const float w1 = __uint_as_float(pk.y & 0xFFFF0000u);
            const float w2 = __uint_as_float(pk.z & 0xFFFF0000u);
            const float w3 = __uint_as_float(pk.w & 0xFFFF0000u);
#pragma unroll
            for (int j = 0; j < 8; ++j) {
                a[j] += w0 * bf2f(v0[j]) + w1 * bf2f(v1[j]);
                a[j] += w2 * bf2f(v2[j]) + w3 * bf2f(v3[j]);
            }
        }
        for (; it < cnt; ++it) {               // <=3 cleanup iterations
            const unsigned int p = ep[it];
            ushort8 v = *(const ushort8*)(xb + (size_t)(p & 0xFFFFu) * D_FEAT + xoff);
            const float wv = __uint_as_float(p & 0xFFFF0000u);
#pragma unroll
            for (int j = 0; j < 8; ++j) a[j] += wv * bf2f(v[j]);
        }

        ushort8 o;
#pragma unroll
        for (int j = 0; j < 8; ++j) o[j] = f2bf(a[j]);
        *(ushort8*)&h[lr][s * D_FEAT + xoff] = o;
    }
    __syncthreads();

    // ---- phase 2: out_tile[16][256] = h @ W; wave -> 2 n-tiles ----
    const int cit = lane & 15;
    const int kgrp = (lane >> 4) * 8;

    f32x4 acc[2];
#pragma unroll
    for (int j = 0; j < 2; ++j) acc[j] = (f32x4){0.f, 0.f, 0.f, 0.f};

#pragma unroll
    for (int kk = 0; kk < KDIM / 32; ++kk) {   // 24 k-steps
        const int k0 = kk * 32;
        short8 av = *(const short8*)&h[cit][k0 + kgrp];
        const int s = k0 >> 8;
        const int kp = (k0 & 255) + kgrp;
        const short* bbase = (const short*)wt + (size_t)s * D_FEAT * OUT_DIM
                           + (size_t)cit * D_FEAT + kp;
#pragma unroll
        for (int j = 0; j < 2; ++j) {
            const int nt = wid * 2 + j;
            short8 bv = *(const short8*)(bbase + (size_t)nt * 16 * D_FEAT);
            acc[j] = __builtin_amdgcn_mfma_f32_16x16x32_bf16(av, bv, acc[j], 0, 0, 0);
        }
    }

    // C-write (round-2-verified mapping): row = rbase+r, col = nt*16 + cit
    const int rbase = (lane >> 4) * 4;
#pragma unroll
    for (int j = 0; j < 2; ++j) {
        const int col = (wid * 2 + j) * 16 + cit;
#pragma unroll
        for (int r = 0; r < 4; ++r) {
            out[(size_t)(n0 + rbase + r) * OUT_DIM + col] = acc[j][r];
        }
    }
}

extern "C" void kernel_launch(void* const* d_in, const int* in_sizes, int n_in,
                              void* d_out, int out_size, void* d_ws, size_t ws_size,
                              hipStream_t stream) {
    const float* x        = (const float*)d_in[0];
    const int*   edge_src = (const int*)d_in[1];
    const int*   edge_dst = (const int*)d_in[2];
    const float* edge_w   = (const float*)d_in[3];
    const float* W        = (const float*)d_in[4];
    float* out = (float*)d_out;

    char* ws = (char*)d_ws;
    unsigned short* xb     = (unsigned short*)(ws);              // 10,240,000 B
    unsigned short* wt     = (unsigned short*)(ws + 10240000);   //    393,216 B
    int*            cursor = (int*)(ws + 10633216);              //    240,000 B
    unsigned int*   epack  = (unsigned int*)(ws + 10873216);     // 15,360,000 B

    hipMemsetAsync(cursor, 0, 240000, stream);

    prep<<<NB_X + NB_W + NB_F, 256, 0, stream>>>(x, W, edge_src, edge_dst, edge_w,
                                                 xb, wt, cursor, epack);

    fused_gather_gemm<<<N_NODES / TILE, 512, 0, stream>>>(xb, wt, cursor, epack, out);
}